// Round 14
// baseline (168.976 us; speedup 1.0000x reference)
//
#include <hip/hip_runtime.h>
#include <math.h>

#define NN 500
#define TT 48
#define NT 24000   // NN*TT
#define NF4 6000   // NT/4

typedef float f4v __attribute__((ext_vector_type(4)));

// ---------- kernel 0a: row sums of s ----------
__global__ void k_srow(const float* __restrict__ s, float* __restrict__ srow) {
    int r = blockIdx.x;
    int l = threadIdx.x;
    float v = 0.f;
    for (int j = l; j < NN; j += 64) v += s[r * NN + j];
    #pragma unroll
    for (int o = 32; o; o >>= 1) v += __shfl_xor(v, o);
    if (l == 0) srow[r] = v;
}

// ---------- kernel 1: PERSISTENT-BLOCK DMA-pipelined softmax partials ----------
// 1024 blocks (4/CU, co-resident), each grid-strides 8 (bc,half) units.
// Rationale (r13 post-mortem): 8192 short-lived blocks = 32 block-generations
// per CU, each with a dead-pipe prologue/epilogue (~1.2-1.5 us x 32 ~= the
// +40 us p1 carries over k_lo). Persistent blocks amortize srow staging 8x
// and let the global_load_lds double-buffer pipeline run ACROSS unit
// boundaries -- the VMEM queue never drains mid-kernel. vmcnt immediates
// account for the 2 epilogue stores in the in-order queue.
__launch_bounds__(256, 4)
__global__ void k_p1(const float* __restrict__ x, const float* __restrict__ srow,
                     float* __restrict__ xraw, float* __restrict__ mz) {
    __shared__ float p[3072];                 // 4 waves x 768 private floats
    __shared__ __align__(16) float sr[512];   // srow staged (500 used)
    __shared__ __align__(16) float stg[4][2][768];  // per-wave double buffer
    int g = blockIdx.x;                       // 0..1023
    int tid = threadIdx.x;
    int w = tid >> 6, l = tid & 63;
    int fl0 = w * 768 + l;

    sr[tid] = srow[(tid < NN) ? tid : (NN - 1)];
    int t2 = tid + 256;
    sr[t2] = (t2 < NN) ? srow[t2] : 0.f;
    __syncthreads();                          // once per kernel (amortized 8x)

#define SB() __builtin_amdgcn_sched_barrier(0)

#define STAGE(U, s) do {                                                      \
        int bcS_ = (U) >> 1;                                                  \
        int rowbS_ = ((U) & 1) * 3072 + w * 768;                              \
        const f4v* xpS_ = (const f4v*)x + (size_t)bcS_ * NF4;                 \
        _Pragma("unroll")                                                     \
        for (int k_ = 0; k_ < 3; k_++) {                                      \
            int f_ = rowbS_ + (s) * 192 + k_ * 64 + l;                        \
            int fc_ = (f_ < NF4) ? f_ : (NF4 - 1);                            \
            __builtin_amdgcn_global_load_lds(                                 \
                (const __attribute__((address_space(1))) void*)(xpS_ + fc_),  \
                (__attribute__((address_space(3))) void*)&stg[w][(s) & 1][k_ * 256], \
                16, 0, 0);                                                    \
        }                                                                     \
    } while (0)

#define VMCNT(n) do {                                                         \
        asm volatile("s_waitcnt vmcnt(" #n ")" ::: "memory");                 \
        __builtin_amdgcn_sched_barrier(0);                                    \
    } while (0)

    float sf[12], ml[12], m;

#define COMPU(U, s) do {                                                      \
        int rowbC_ = ((U) & 1) * 3072 + w * 768;                              \
        _Pragma("unroll")                                                     \
        for (int k_ = 0; k_ < 3; k_++) {                                      \
            int i_ = 3 * (s) + k_;                                            \
            int f_ = rowbC_ + (s) * 192 + k_ * 64 + l;                        \
            int fc_ = (f_ < NF4) ? f_ : (NF4 - 1);                            \
            float msk_ = (f_ < NF4) ? 1.f : 0.f;                              \
            float4 xv = ((const float4*)stg[w][(s) & 1])[k_ * 64 + l];        \
            int kk_ = 4 * fc_;                                                \
            int ti_ = kk_ / 500;                                              \
            int v_  = kk_ - ti_ * 500;                                        \
            float tt_ = (float)(TT - 1 - ti_) * 0.8f;                         \
            float4 sv = *(const float4*)(sr + v_);                            \
            float y0 = fmaxf(xv.x * (tt_ + sv.x) * 0.125f, 0.f);              \
            float y1 = fmaxf(xv.y * (tt_ + sv.y) * 0.125f, 0.f);              \
            float y2 = fmaxf(xv.z * (tt_ + sv.z) * 0.125f, 0.f);              \
            float y3 = fmaxf(xv.w * (tt_ + sv.w) * 0.125f, 0.f);              \
            float mm_ = fmaxf(fmaxf(y0, y1), fmaxf(y2, y3));                  \
            float sfi_ = __expf(y0 - mm_) + __expf(y1 - mm_)                  \
                       + __expf(y2 - mm_) + __expf(y3 - mm_);                 \
            sf[i_] = sfi_ * msk_;                                             \
            ml[i_] = mm_;                                                     \
            m = fmaxf(m, mm_);                                                \
        }                                                                     \
    } while (0)

#define EPIL(U) do {                                                          \
        _Pragma("unroll")                                                     \
        for (int o_ = 32; o_; o_ >>= 1) m = fmaxf(m, __shfl_xor(m, o_));      \
        float tot_ = 0.f;                                                     \
        _Pragma("unroll")                                                     \
        for (int i_ = 0; i_ < 12; i_++) {                                     \
            float cf_ = sf[i_] * __expf(ml[i_] - m);                          \
            p[fl0 + i_ * 64] = cf_;                                           \
            tot_ += cf_;                                                      \
        }                                                                     \
        _Pragma("unroll")                                                     \
        for (int o_ = 32; o_; o_ >>= 1) tot_ += __shfl_xor(tot_, o_);         \
        asm volatile("s_waitcnt lgkmcnt(0)" ::: "memory");                    \
        __builtin_amdgcn_sched_barrier(0);                                    \
        int bcE_ = (U) >> 1, halfE_ = (U) & 1;                                \
        int n_ = halfE_ * 256 + w * 64 + l;                                   \
        if (n_ < NN) {                                                        \
            const float4* pp_ = (const float4*)(p + w * 768 + l * 12);        \
            float4 a_ = pp_[0], b_ = pp_[1], c_ = pp_[2];                     \
            float sn_ = a_.x + a_.y + a_.z + a_.w + b_.x + b_.y + b_.z + b_.w \
                      + c_.x + c_.y + c_.z + c_.w;                            \
            xraw[(size_t)bcE_ * NN + n_] = sn_;                               \
        }                                                                     \
        if (l == 0) {                                                         \
            int wv_ = halfE_ * 4 + w;                                         \
            mz[((size_t)bcE_ * 8 + wv_) * 2 + 0] = m;                         \
            mz[((size_t)bcE_ * 8 + wv_) * 2 + 1] = tot_;                      \
        }                                                                     \
    } while (0)

    int U = g;
    STAGE(U, 0);
    STAGE(U, 1);

    // ---- first unit: queue holds loads only -> vmcnt 3,3,3,3 ----
    {
        int Un = U + 1024;
        m = 0.f;
        VMCNT(3); COMPU(U, 0); SB(); STAGE(U, 2);
        VMCNT(3); COMPU(U, 1); SB(); STAGE(U, 3);
        VMCNT(3); COMPU(U, 2); SB(); STAGE(Un, 0);
        VMCNT(3); COMPU(U, 3); SB(); STAGE(Un, 1);
        EPIL(U);                  // queue exits as [next0(3), next1(3), st, st]
        U = Un;
    }
    // ---- middle units: 2 stores ride in the in-order queue -> 5,5,3,3 ----
    #pragma unroll 1
    for (int it = 1; it < 7; ++it) {
        int Un = U + 1024;
        m = 0.f;
        VMCNT(5); COMPU(U, 0); SB(); STAGE(U, 2);
        VMCNT(5); COMPU(U, 1); SB(); STAGE(U, 3);
        VMCNT(3); COMPU(U, 2); SB(); STAGE(Un, 0);
        VMCNT(3); COMPU(U, 3); SB(); STAGE(Un, 1);
        EPIL(U);
        U = Un;
    }
    // ---- last unit: no next-unit stages -> 5,5,3,0 ----
    {
        m = 0.f;
        VMCNT(5); COMPU(U, 0); SB(); STAGE(U, 2);
        VMCNT(5); COMPU(U, 1); SB(); STAGE(U, 3);
        VMCNT(3); COMPU(U, 2);
        VMCNT(0); COMPU(U, 3);
        EPIL(U);
    }

#undef SB
#undef STAGE
#undef VMCNT
#undef COMPU
#undef EPIL
}

// ---------- kernel 1b: fold per-wave (Mw, Zw) into factors (unchanged) ----------
__global__ void k_mz(const float* __restrict__ mz, float* __restrict__ factor) {
    int bc = blockIdx.x * 256 + threadIdx.x;     // 16 blocks x 256 = 4096
    float Mw[8], Zw[8];
    float M = 0.f;
    #pragma unroll
    for (int wv = 0; wv < 8; wv++) {
        Mw[wv] = mz[((size_t)bc * 8 + wv) * 2 + 0];
        Zw[wv] = mz[((size_t)bc * 8 + wv) * 2 + 1];
        M = fmaxf(M, Mw[wv]);
    }
    float Z = 0.f;
    float e[8];
    #pragma unroll
    for (int wv = 0; wv < 8; wv++) {
        e[wv] = __expf(Mw[wv] - M);
        Z += Zw[wv] * e[wv];
    }
    float invZ = 1.f / Z;
    #pragma unroll
    for (int wv = 0; wv < 8; wv++)
        factor[(size_t)bc * 8 + wv] = e[wv] * invZ;
}

// ---------- kernel 2: gram fused with row softmax (unchanged) ----------
__launch_bounds__(512, 4)
__global__ void k_p2(const float* __restrict__ xraw, const float* __restrict__ factor,
                     float* __restrict__ out) {
    __shared__ __align__(16) float Xs[32 * NN + 16];
    int b = blockIdx.y;
    int rt8 = blockIdx.x;   // 0..7
    int tid = threadIdx.x;

    int rt = tid >> 6, cx = tid & 63;
    int r0 = rt8 * 64 + rt * 8;
    int cb0 = cx * 4, cb1 = cx * 4 + 256;

    float acc[8][8];
    #pragma unroll
    for (int i = 0; i < 8; i++)
        #pragma unroll
        for (int j = 0; j < 8; j++) acc[i][j] = 0.f;

    for (int cbk = 0; cbk < 2; cbk++) {
        const float4* src4 = (const float4*)(xraw + ((size_t)b * 64 + 32 * cbk) * NN);
        const float* fac = factor + ((size_t)b * 64 + 32 * cbk) * 8;
        __syncthreads();                 // protect previous Xs use
        #pragma unroll
        for (int i = 0; i < 8; i++) {
            int idx = tid + i * 512;
            if (idx < 4000) {
                int c = idx / 125;       // magic-mul div (125 float4 per channel)
                int n4 = idx - c * 125;
                float fct = fac[c * 8 + (n4 >> 4)];
                float4 v = src4[idx];
                v.x *= fct; v.y *= fct; v.z *= fct; v.w *= fct;
                ((float4*)Xs)[idx] = v;
            }
        }
        if (tid < 16) Xs[32 * NN + tid] = 0.f;   // zero the guard pad
        __syncthreads();

        #pragma unroll 4
        for (int c = 0; c < 32; c++) {
            const float* row = Xs + c * NN;
            float4 a0 = *(const float4*)(row + r0);       // broadcast (uniform addr)
            float4 a1 = *(const float4*)(row + r0 + 4);
            float4 b0 = *(const float4*)(row + cb0);      // lanes contiguous 16B
            float4 b1 = *(const float4*)(row + cb1);
            float av[8] = {a0.x, a0.y, a0.z, a0.w, a1.x, a1.y, a1.z, a1.w};
            float bv[8] = {b0.x, b0.y, b0.z, b0.w, b1.x, b1.y, b1.z, b1.w};
            #pragma unroll
            for (int i = 0; i < 8; i++)
                #pragma unroll
                for (int j = 0; j < 8; j++)
                    acc[i][j] = fmaf(av[i], bv[j], acc[i][j]);
        }
    }

    bool c1v = (cx <= 60);
    size_t ob = (size_t)b * (NN * NN);
    #pragma unroll 1
    for (int ri = 0; ri < 8; ri++) {
        int r = r0 + ri;
        if (r >= NN) break;         // wave-uniform
        float u[8];
        #pragma unroll
        for (int j = 0; j < 8; j++) u[j] = fmaxf(acc[ri][j], 0.f) * 0.125f;
        float mx = fmaxf(fmaxf(u[0], u[1]), fmaxf(u[2], u[3]));
        if (c1v) mx = fmaxf(mx, fmaxf(fmaxf(u[4], u[5]), fmaxf(u[6], u[7])));
        #pragma unroll
        for (int o = 32; o; o >>= 1) mx = fmaxf(mx, __shfl_xor(mx, o));

        float e[8];
        float es = 0.f;
        #pragma unroll
        for (int j = 0; j < 4; j++) { e[j] = __expf(u[j] - mx); es += e[j]; }
        if (c1v) {
            #pragma unroll
            for (int j = 4; j < 8; j++) { e[j] = __expf(u[j] - mx); es += e[j]; }
        }
        #pragma unroll
        for (int o = 32; o; o >>= 1) es += __shfl_xor(es, o);
        float inv = 1.f / es;

        float4 w0 = make_float4(e[0] * inv, e[1] * inv, e[2] * inv, e[3] * inv);
        *(float4*)(out + ob + (size_t)r * NN + cb0) = w0;
        if (c1v) {
            float4 w1 = make_float4(e[4] * inv, e[5] * inv, e[6] * inv, e[7] * inv);
            *(float4*)(out + ob + (size_t)r * NN + cb1) = w1;
        }
    }
}

extern "C" void kernel_launch(void* const* d_in, const int* in_sizes, int n_in,
                              void* d_out, int out_size, void* d_ws, size_t ws_size,
                              hipStream_t stream) {
    const float* x = (const float*)d_in[0];   // [64,64,500,48]
    const float* s = (const float*)d_in[1];   // [500,500]
    float* out = (float*)d_out;               // [64,500,500]
    float* wsf = (float*)d_ws;

    float* srow   = wsf;                        // 500 floats
    float* xraw   = wsf + 32768;                // 2,048,000 floats
    float* mz     = wsf + 32768 + 2048000;      // 65,536 floats
    float* factor = wsf + 32768 + 2048000 + 65536;  // 32,768 floats

    k_srow<<<NN, 64, 0, stream>>>(s, srow);
    k_p1<<<1024, 256, 0, stream>>>(x, srow, xraw, mz);
    k_mz<<<16, 256, 0, stream>>>(mz, factor);
    dim3 g2(8, 64);
    k_p2<<<g2, 512, 0, stream>>>(xraw, factor, out);
}